// Round 1
// baseline (1124.312 us; speedup 1.0000x reference)
//
#include <hip/hip_runtime.h>

// Fused: conv1x1(48->288) -> depthwise3x3 -> split q,k,v -> per-64px-row-segment
// 8x8 circular conv (the rfft2/irfft2 product) -> LayerNorm over 96 ch -> v*normed
// -> conv1x1(96->48).
//
// Patch decode: reshape(B,C2,32,32,8,8) of [B,C2,256,256] means patch (hp,wp)
// element (pi,pj) sits at h = 8*hp + wp/4, w = (wp%4)*64 + 8*pi + pj, i.e. each
// FFT patch is a contiguous 64-pixel row segment. Block = (wseg, h, b).

#define B_   4
#define C_   48
#define C6_  288
#define C2_  96
#define H_   256
#define W_   256
#define NCL    12     // c2-channels per chunk
#define NCHUNK 8      // 96/12
#define CH6    36     // 3*NCL c6-channels per chunk (q,k,v groups)
#define ROWS   68     // padded row width (66 valid: cols w0-1 .. w0+64)
#define PSTR   208    // padded per-channel pixel stride (3*68=204 -> 208)
#define NPG    26     // pixel groups of 8 (208/8)

// ---- LDS layout (bytes) ----
#define OFF_XS   0                        // ushort xs [48][208]          = 19968
#define OFF_HID  19968                    // ushort hid[36][208]          = 14976
#define OFF_U    (19968+14976)            // union: wchT ushort[48][36]=3456 | qs,ks ushort[2][12][64]=3072
#define OFF_O    (OFF_U+3456)             // ushort o  [96][64]           = 12288
#define OFF_V    (OFF_O+12288)            // ushort v  [96][64]           = 12288
#define OFF_LN   (OFF_V+12288)            // float mu[64], rs[64]         = 512
#define SMEM_BYTES (OFF_LN+512)           // = 63488 (< 64 KiB)
// aliases (after chunk loop): a float[96][64]=24576 at offset 0 (over xs+hid);
// woT float[96][48]=18432 at OFF_O (over o+v, loaded after a is written).

__device__ __forceinline__ float bf2f(unsigned short u) {
  return __uint_as_float(((unsigned int)u) << 16);
}
__device__ __forceinline__ unsigned short f2bf(float f) {  // RNE
  unsigned int x = __float_as_uint(f);
  x += 0x7FFFu + ((x >> 16) & 1u);
  return (unsigned short)(x >> 16);
}

__global__ __launch_bounds__(256, 2) void fsas_fused(
    const float* __restrict__ x,   const float* __restrict__ wh,
    const float* __restrict__ bh,  const float* __restrict__ wdw,
    const float* __restrict__ bdw, const float* __restrict__ gam,
    const float* __restrict__ bet, const float* __restrict__ wo,
    const float* __restrict__ bo,  float* __restrict__ y)
{
  __shared__ __align__(16) char smem[SMEM_BYTES];
  unsigned short* xs   = (unsigned short*)(smem + OFF_XS);
  unsigned short* hid  = (unsigned short*)(smem + OFF_HID);
  unsigned short* wchT = (unsigned short*)(smem + OFF_U);
  unsigned short* qs   = (unsigned short*)(smem + OFF_U);              // [12][64]
  unsigned short* ks   = (unsigned short*)(smem + OFF_U + NCL*64*2);   // [12][64]
  unsigned short* osh  = (unsigned short*)(smem + OFF_O);              // [96][64]
  unsigned short* vsh  = (unsigned short*)(smem + OFF_V);              // [96][64]
  float* mu  = (float*)(smem + OFF_LN);
  float* rs  = (float*)(smem + OFF_LN + 256);
  float* ash = (float*)(smem);             // alias [96][64] fp32
  float* woT = (float*)(smem + OFF_O);     // alias [96][48] fp32

  const int tid  = threadIdx.x;
  const int wseg = blockIdx.x;   // 0..3
  const int h    = blockIdx.y;   // 0..255
  const int b    = blockIdx.z;   // 0..3
  const int w0   = wseg * 64;

  // ---- Stage A: x halo (48 ch x 3 rows x 66 cols) -> bf16 LDS (pads = 0) ----
  for (int idx = tid; idx < C_ * PSTR; idx += 256) {
    int c  = idx / PSTR;
    int r2 = idx - c * PSTR;
    int rr = r2 / ROWS;            // 0..3 (3 = tail pad)
    int cc = r2 - rr * ROWS;
    float val = 0.f;
    if (rr < 3 && cc < 66) {
      int gr = h - 1 + rr;
      int gc = w0 - 1 + cc;
      if (gr >= 0 && gr < H_ && gc >= 0 && gc < W_)
        val = x[(((b * C_) + c) * H_ + gr) * W_ + gc];
    }
    xs[idx] = f2bf(val);
  }
  __syncthreads();

  // ---- chunk loop: 12 c2-channels (36 c6-channels) at a time ----
  for (int chunk = 0; chunk < NCHUNK; ++chunk) {
    const int qbase = chunk * NCL;

    // load wchT[c][cl] = wh[c6*48+c]  (c6 = group*96 + qbase + lc)
    for (int idx = tid; idx < C_ * CH6; idx += 256) {
      int cl = idx / C_;
      int c  = idx - cl * C_;
      int c6 = (cl / NCL) * C2_ + qbase + (cl % NCL);
      wchT[c * CH6 + cl] = f2bf(wh[c6 * C_ + c]);
    }
    __syncthreads();

    // B1: hidden GEMM. unit = 4 c6-channels x 8 pixels. 9*26 = 234 units.
    if (tid < 9 * NPG) {
      const int cgrp = tid / NPG;
      const int pg   = tid - cgrp * NPG;
      const int cl0  = cgrp * 4;
      const int p0   = pg * 8;

      bool valid[8];
      #pragma unroll
      for (int pi = 0; pi < 8; ++pi) {
        int p  = p0 + pi;
        int rr = p / ROWS;
        int cc = p - rr * ROWS;
        int gr = h - 1 + rr;
        int gc = w0 - 1 + cc;
        valid[pi] = (rr < 3) && (cc < 66) &&
                    (gr >= 0) && (gr < H_) && (gc >= 0) && (gc < W_);
      }

      float acc[4][8];
      #pragma unroll
      for (int ci = 0; ci < 4; ++ci) {
        int cl = cl0 + ci;
        int c6 = (cl / NCL) * C2_ + qbase + (cl % NCL);
        float bias = bh[c6];
        #pragma unroll
        for (int pi = 0; pi < 8; ++pi) acc[ci][pi] = bias;
      }

      for (int c = 0; c < C_; ++c) {
        const ushort4* xp = (const ushort4*)(xs + c * PSTR + p0);
        ushort4 xa = xp[0];
        ushort4 xb = xp[1];
        ushort4 wv = *(const ushort4*)(wchT + c * CH6 + cl0);
        float xf[8] = {bf2f(xa.x), bf2f(xa.y), bf2f(xa.z), bf2f(xa.w),
                       bf2f(xb.x), bf2f(xb.y), bf2f(xb.z), bf2f(xb.w)};
        float wf[4] = {bf2f(wv.x), bf2f(wv.y), bf2f(wv.z), bf2f(wv.w)};
        #pragma unroll
        for (int ci = 0; ci < 4; ++ci)
          #pragma unroll
          for (int pi = 0; pi < 8; ++pi)
            acc[ci][pi] += wf[ci] * xf[pi];
      }

      // store hid (mask: SAME padding pads *hidden* with zeros, not x)
      #pragma unroll
      for (int ci = 0; ci < 4; ++ci) {
        ushort4 pa = make_ushort4(
            valid[0] ? f2bf(acc[ci][0]) : (unsigned short)0,
            valid[1] ? f2bf(acc[ci][1]) : (unsigned short)0,
            valid[2] ? f2bf(acc[ci][2]) : (unsigned short)0,
            valid[3] ? f2bf(acc[ci][3]) : (unsigned short)0);
        ushort4 pb = make_ushort4(
            valid[4] ? f2bf(acc[ci][4]) : (unsigned short)0,
            valid[5] ? f2bf(acc[ci][5]) : (unsigned short)0,
            valid[6] ? f2bf(acc[ci][6]) : (unsigned short)0,
            valid[7] ? f2bf(acc[ci][7]) : (unsigned short)0);
        *(ushort4*)(hid + (cl0 + ci) * PSTR + p0)     = pa;
        *(ushort4*)(hid + (cl0 + ci) * PSTR + p0 + 4) = pb;
      }
    }
    __syncthreads();

    // B2: depthwise 3x3 -> qs / ks / v   (36*64 = 2304 outputs, 9 per thread)
    for (int idx = tid; idx < CH6 * 64; idx += 256) {
      int cl  = idx >> 6;
      int pp  = idx & 63;
      int grp = cl / NCL;
      int lc  = cl - grp * NCL;
      int c6  = grp * C2_ + qbase + lc;
      float acc = bdw[c6];
      const float* wd = wdw + c6 * 9;
      #pragma unroll
      for (int di = 0; di < 3; ++di)
        #pragma unroll
        for (int dj = 0; dj < 3; ++dj)
          acc += wd[di * 3 + dj] * bf2f(hid[cl * PSTR + di * ROWS + pp + dj]);
      unsigned short r = f2bf(acc);
      if (grp == 0)      qs[lc * 64 + pp] = r;
      else if (grp == 1) ks[lc * 64 + pp] = r;
      else               vsh[(qbase + lc) * 64 + pp] = r;
    }
    __syncthreads();

    // B3: 8x8 circular convolution per channel. unit = (channel, out-row u).
    if (tid < NCL * 8) {
      int cl = tid >> 3;
      int u  = tid & 7;
      float acc[8];
      #pragma unroll
      for (int t = 0; t < 8; ++t) acc[t] = 0.f;
      #pragma unroll
      for (int i = 0; i < 8; ++i) {
        int r = (u - i) & 7;
        const ushort4* qp = (const ushort4*)(qs + cl * 64 + i * 8);
        const ushort4* kp = (const ushort4*)(ks + cl * 64 + r * 8);
        ushort4 qa = qp[0], qb = qp[1];
        ushort4 ka = kp[0], kb = kp[1];
        float qf[8] = {bf2f(qa.x), bf2f(qa.y), bf2f(qa.z), bf2f(qa.w),
                       bf2f(qb.x), bf2f(qb.y), bf2f(qb.z), bf2f(qb.w)};
        float kf[8] = {bf2f(ka.x), bf2f(ka.y), bf2f(ka.z), bf2f(ka.w),
                       bf2f(kb.x), bf2f(kb.y), bf2f(kb.z), bf2f(kb.w)};
        #pragma unroll
        for (int j = 0; j < 8; ++j)
          #pragma unroll
          for (int vv = 0; vv < 8; ++vv)
            acc[vv] += qf[j] * kf[(vv - j) & 7];
      }
      int c2 = qbase + cl;
      ushort4 pa = make_ushort4(f2bf(acc[0]), f2bf(acc[1]), f2bf(acc[2]), f2bf(acc[3]));
      ushort4 pb = make_ushort4(f2bf(acc[4]), f2bf(acc[5]), f2bf(acc[6]), f2bf(acc[7]));
      *(ushort4*)(osh + c2 * 64 + u * 8)     = pa;
      *(ushort4*)(osh + c2 * 64 + u * 8 + 4) = pb;
    }
    __syncthreads();
  }

  // ---- LayerNorm over channels per pixel ----
  if (tid < 64) {
    float s = 0.f, s2 = 0.f;
    for (int c = 0; c < C2_; ++c) {
      float ov = bf2f(osh[c * 64 + tid]);
      s += ov; s2 += ov * ov;
    }
    float m   = s * (1.f / 96.f);
    float var = s2 * (1.f / 96.f) - m * m;
    mu[tid] = m;
    rs[tid] = rsqrtf(var + 1e-5f);
  }
  __syncthreads();

  // a = v * (normed*gamma + beta), fp32, aliased over xs/hid
  for (int idx = tid; idx < C2_ * 64; idx += 256) {
    int c  = idx >> 6;
    int pp = idx & 63;
    float ov = bf2f(osh[c * 64 + pp]);
    float nv = (ov - mu[pp]) * rs[pp] * gam[c] + bet[c];
    ash[idx] = nv * bf2f(vsh[idx]);
  }
  __syncthreads();

  // load w_out transposed (over o+v region, now dead)
  for (int idx = tid; idx < C2_ * C_; idx += 256) {
    int c2 = idx / C_;
    int co = idx - c2 * C_;
    woT[c2 * C_ + co] = wo[co * C2_ + c2];
  }
  __syncthreads();

  // ---- final conv1x1 (96->48): unit = 4 co x 4 px, 12*16 = 192 units ----
  if (tid < 192) {
    int cg  = tid >> 4;
    int pg  = tid & 15;
    int co0 = cg * 4;
    int pp0 = pg * 4;
    float acc[4][4];
    #pragma unroll
    for (int ci = 0; ci < 4; ++ci) {
      float bb = bo[co0 + ci];
      #pragma unroll
      for (int pi = 0; pi < 4; ++pi) acc[ci][pi] = bb;
    }
    for (int c2 = 0; c2 < C2_; ++c2) {
      float4 av = *(const float4*)(ash + c2 * 64 + pp0);
      float4 wv = *(const float4*)(woT + c2 * C_ + co0);
      float af[4] = {av.x, av.y, av.z, av.w};
      float wf[4] = {wv.x, wv.y, wv.z, wv.w};
      #pragma unroll
      for (int ci = 0; ci < 4; ++ci)
        #pragma unroll
        for (int pi = 0; pi < 4; ++pi)
          acc[ci][pi] += wf[ci] * af[pi];
    }
    #pragma unroll
    for (int ci = 0; ci < 4; ++ci) {
      float4 r = make_float4(acc[ci][0], acc[ci][1], acc[ci][2], acc[ci][3]);
      *(float4*)(y + (((b * C_) + co0 + ci) * H_ + h) * W_ + w0 + pp0) = r;
    }
  }
}

extern "C" void kernel_launch(void* const* d_in, const int* in_sizes, int n_in,
                              void* d_out, int out_size, void* d_ws, size_t ws_size,
                              hipStream_t stream) {
  const float* x   = (const float*)d_in[0];
  const float* wh  = (const float*)d_in[1];
  const float* bh  = (const float*)d_in[2];
  const float* wdw = (const float*)d_in[3];
  const float* bdw = (const float*)d_in[4];
  const float* g   = (const float*)d_in[5];
  const float* be  = (const float*)d_in[6];
  const float* wo  = (const float*)d_in[7];
  const float* bo  = (const float*)d_in[8];
  float* y = (float*)d_out;
  dim3 grid(4, H_, B_);   // (wseg, h, b) = 4096 blocks
  fsas_fused<<<grid, 256, 0, stream>>>(x, wh, bh, wdw, bdw, g, be, wo, bo, y);
}

// Round 2
// 758.574 us; speedup vs baseline: 1.4821x; 1.4821x over previous
//
#include <hip/hip_runtime.h>

// Fused: conv1x1(48->288, MFMA) -> depthwise3x3 (VALU) -> split q,k,v ->
// per-64px-row-segment 8x8 circular conv (VALU) -> LayerNorm over 96 ch ->
// v*normed -> conv1x1(96->48, MFMA).
//
// Patch decode (verified R1): reshape(B,C2,32,32,8,8) => each FFT patch is a
// contiguous 64-pixel row segment viewed as 8x8. Block = (wseg, h, b).
//
// MFMA 16x16x32 bf16 layouts (HW-verified per guide m89/m118):
//   A[m=lane&15][k=quad*8+j]   B[k=quad*8+j][n=lane&15]
//   D: col=lane&15, row=quad*4+reg

#define B_   4
#define C_   48
#define H_   256
#define W_   256
#define NCL    12      // c2-channels per chunk
#define NCHUNK 8
#define ROWS   68      // halo row width (66 valid)
#define NPX    208     // 3*68 + 4 junk tail, = 13 n-tiles of 16
#define XT_STR 52      // xs_t leading-dim pad (8B-aligned rows, spread banks)
#define HID_STR 212    // hid pixel stride (bank spread for quad-strided stores)
#define AT_STR 108     // a_t leading-dim pad

// ---- LDS offsets (bytes), all 16B-aligned ----
#define OFF_XT   0                 // ushort xs_t[208][52] = 21632
#define OFF_HID  21632             // ushort hid [36][212] = 15264
#define OFF_QS   36896             // ushort qs  [12][64]  = 1536
#define OFF_KS   38432             // ushort ks  [12][64]  = 1536
#define OFF_OSH  39968             // ushort osh [96][64]  = 12288
#define OFF_VSH  52256             // ushort vsh [96][64]  = 12288
#define OFF_MU   64544             // float mu[64]
#define OFF_RS   64800             // float rs[64]
#define SMEM_BYTES 65056           // < 65536
// alias after chunk loop: a_t ushort[64][108]=13824 over xs_t (dead)

typedef __attribute__((ext_vector_type(8))) short short8;
typedef __attribute__((ext_vector_type(4))) float floatx4;

union U128 { unsigned long long u[2]; short8 s; };

__device__ __forceinline__ float bf2f(unsigned short u) {
  return __uint_as_float(((unsigned int)u) << 16);
}
__device__ __forceinline__ unsigned short f2bf(float f) {  // RNE
  unsigned int x = __float_as_uint(f);
  x += 0x7FFFu + ((x >> 16) & 1u);
  return (unsigned short)(x >> 16);
}
__device__ __forceinline__ unsigned long long pack4(float a, float b, float c, float d) {
  return (unsigned long long)f2bf(a) | ((unsigned long long)f2bf(b) << 16) |
         ((unsigned long long)f2bf(c) << 32) | ((unsigned long long)f2bf(d) << 48);
}

// ---- prologue: fp32 weights -> padded bf16 in d_ws ----
// w1[chunk][48][64]: w1[(chunk*48+m)*64+k] = (m<36 && k<48) ? wh[c6*48+k] : 0,
//   c6 = (m/12)*96 + chunk*12 + (m%12).   (24576 ushorts)
// w2[co][96] = wo (bf16), at w1+24576.    (4608 ushorts)
__global__ void fsas_prep(const float* __restrict__ wh, const float* __restrict__ wo,
                          unsigned short* __restrict__ w1) {
  int idx = blockIdx.x * 256 + threadIdx.x;
  if (idx < 8 * 48 * 64) {
    int k = idx & 63, t = idx >> 6;
    int m = t % 48, ch = t / 48;
    float v = 0.f;
    if (m < 36 && k < 48) {
      int c6 = (m / 12) * 96 + ch * 12 + (m % 12);
      v = wh[c6 * 48 + k];
    }
    w1[idx] = f2bf(v);
  } else {
    int e = idx - 8 * 48 * 64;
    if (e < 48 * 96) w1[24576 + e] = f2bf(wo[e]);
  }
}

__global__ __launch_bounds__(256, 2) void fsas_fused(
    const float* __restrict__ x,   const float* __restrict__ bh,
    const float* __restrict__ wdw, const float* __restrict__ bdw,
    const float* __restrict__ gam, const float* __restrict__ bet,
    const float* __restrict__ bo,  const unsigned short* __restrict__ w1,
    float* __restrict__ y)
{
  __shared__ __align__(16) char smem[SMEM_BYTES];
  unsigned short* xs_t = (unsigned short*)(smem + OFF_XT);
  unsigned short* hid  = (unsigned short*)(smem + OFF_HID);
  unsigned short* qs   = (unsigned short*)(smem + OFF_QS);
  unsigned short* ks   = (unsigned short*)(smem + OFF_KS);
  unsigned short* osh  = (unsigned short*)(smem + OFF_OSH);
  unsigned short* vsh  = (unsigned short*)(smem + OFF_VSH);
  float* mu  = (float*)(smem + OFF_MU);
  float* rs  = (float*)(smem + OFF_RS);
  unsigned short* a_t  = (unsigned short*)(smem);   // alias over xs_t
  const unsigned short* w2 = w1 + 24576;

  const int tid  = threadIdx.x;
  const int wseg = blockIdx.x;
  const int h    = blockIdx.y;
  const int b    = blockIdx.z;
  const int w0   = wseg * 64;
  const int lane = tid & 63;
  const int wv   = tid >> 6;
  const int ln   = lane & 15;
  const int quad = lane >> 4;

  // ---- Stage A: x halo -> xs_t[p][c] bf16 (pixel-major for MFMA B-frags) ----
  for (int idx = tid; idx < C_ * NPX; idx += 256) {
    int c = idx / NPX;
    int p = idx - c * NPX;
    int rr = p / ROWS, cc = p - rr * ROWS;
    float val = 0.f;
    if (rr < 3 && cc < 66) {
      int gr = h - 1 + rr, gc = w0 - 1 + cc;
      if (gr >= 0 && gr < H_ && gc >= 0 && gc < W_)
        val = x[(((b * C_) + c) * H_ + gr) * W_ + gc];
    }
    xs_t[p * XT_STR + c] = f2bf(val);
  }
  __syncthreads();

  for (int chunk = 0; chunk < NCHUNK; ++chunk) {
    const int qbase = chunk * NCL;

    // ---- B1: hidden GEMM via MFMA. M=48(36 real) x N=208 x K=48(pad 64) ----
    short8 afr[3][2];
    float bias[3][4];
    #pragma unroll
    for (int mt = 0; mt < 3; ++mt) {
      #pragma unroll
      for (int ksi = 0; ksi < 2; ++ksi)
        afr[mt][ksi] = *(const short8*)(w1 + ((chunk * 48 + mt * 16 + ln) * 64 + ksi * 32 + quad * 8));
      #pragma unroll
      for (int r = 0; r < 4; ++r) {
        int m = mt * 16 + quad * 4 + r;
        bias[mt][r] = (m < 36) ? bh[(m / 12) * 96 + qbase + (m % 12)] : 0.f;
      }
    }
    for (int nt = wv; nt < 13; nt += 4) {
      int p = nt * 16 + ln;
      int rr = p / ROWS, cc = p - rr * ROWS;
      int gr = h - 1 + rr, gc = w0 - 1 + cc;
      bool pv = (rr < 3) && (cc < 66) && (gr >= 0) && (gr < H_) && (gc >= 0) && (gc < W_);
      const unsigned short* bp = xs_t + p * XT_STR + quad * 8;
      U128 b0, b1;
      b0.u[0] = *(const unsigned long long*)(bp);
      b0.u[1] = *(const unsigned long long*)(bp + 4);
      if (lane < 32) {  // k-step1: quads 0,1 -> k=32..47; quads 2,3 -> zero pad
        b1.u[0] = *(const unsigned long long*)(bp + 32);
        b1.u[1] = *(const unsigned long long*)(bp + 36);
      } else {
        b1.u[0] = 0ull; b1.u[1] = 0ull;
      }
      #pragma unroll
      for (int mt = 0; mt < 3; ++mt) {
        floatx4 acc = {bias[mt][0], bias[mt][1], bias[mt][2], bias[mt][3]};
        acc = __builtin_amdgcn_mfma_f32_16x16x32_bf16(afr[mt][0], b0.s, acc, 0, 0, 0);
        acc = __builtin_amdgcn_mfma_f32_16x16x32_bf16(afr[mt][1], b1.s, acc, 0, 0, 0);
        if (mt < 2 || quad == 0) {   // rows >= 36 are pad
          int mb = mt * 16 + quad * 4;
          #pragma unroll
          for (int r = 0; r < 4; ++r)
            hid[(mb + r) * HID_STR + p] = pv ? f2bf(acc[r]) : (unsigned short)0;
        }
      }
    }
    __syncthreads();

    // ---- B2: depthwise 3x3 (vectorized LDS reads), 288 units of 8 px ----
    for (int u = tid; u < 288; u += 256) {
      int cl = u >> 3, pg = u & 7, p0 = pg * 8;
      int grp = cl / NCL, lc = cl - grp * NCL;
      int c6 = grp * 96 + qbase + lc;
      const float* wd = wdw + c6 * 9;
      float bb = bdw[c6];
      float acc8[8];
      #pragma unroll
      for (int t = 0; t < 8; ++t) acc8[t] = bb;
      #pragma unroll
      for (int di = 0; di < 3; ++di) {
        const unsigned short* hrow = hid + cl * HID_STR + di * ROWS + p0;
        unsigned long long lo = *(const unsigned long long*)(hrow);
        unsigned long long hi = *(const unsigned long long*)(hrow + 4);
        unsigned int ex = *(const unsigned int*)(hrow + 8);
        float hf[10];
        #pragma unroll
        for (int t = 0; t < 4; ++t) hf[t] = bf2f((unsigned short)(lo >> (16 * t)));
        #pragma unroll
        for (int t = 0; t < 4; ++t) hf[4 + t] = bf2f((unsigned short)(hi >> (16 * t)));
        hf[8] = bf2f((unsigned short)ex);
        hf[9] = bf2f((unsigned short)(ex >> 16));
        #pragma unroll
        for (int dj = 0; dj < 3; ++dj) {
          float w = wd[di * 3 + dj];
          #pragma unroll
          for (int t = 0; t < 8; ++t) acc8[t] += w * hf[t + dj];
        }
      }
      unsigned long long lo = pack4(acc8[0], acc8[1], acc8[2], acc8[3]);
      unsigned long long hi = pack4(acc8[4], acc8[5], acc8[6], acc8[7]);
      unsigned short* dst = (grp == 0) ? (qs + lc * 64 + p0)
                          : (grp == 1) ? (ks + lc * 64 + p0)
                          : (vsh + (qbase + lc) * 64 + p0);
      *(unsigned long long*)(dst) = lo;
      *(unsigned long long*)(dst + 4) = hi;
    }
    __syncthreads();

    // ---- B3: 8x8 circular conv, 192 threads: (cl, u, vhalf), branchless ----
    if (tid < 192) {
      int cl = tid >> 4, r4 = tid & 15, uu = r4 >> 1, vh = r4 & 1;
      float a4[4] = {0.f, 0.f, 0.f, 0.f};
      #pragma unroll
      for (int i = 0; i < 8; ++i) {
        short8 qv = *(const short8*)(qs + cl * 64 + i * 8);
        int ri = (uu - i) & 7;
        short8 kv = *(const short8*)(ks + cl * 64 + ri * 8);
        float qf[8], kf[8], kr[8];
        #pragma unroll
        for (int j = 0; j < 8; ++j) {
          qf[j] = bf2f((unsigned short)qv[j]);
          kf[j] = bf2f((unsigned short)kv[j]);
        }
        #pragma unroll
        for (int t = 0; t < 8; ++t) kr[t] = vh ? kf[t ^ 4] : kf[t];  // rotate by 4 if vh
        #pragma unroll
        for (int vvi = 0; vvi < 4; ++vvi)
          #pragma unroll
          for (int j = 0; j < 8; ++j)
            a4[vvi] += qf[j] * kr[(vvi - j) & 7];
      }
      int c2 = qbase + cl;
      *(unsigned long long*)(osh + c2 * 64 + uu * 8 + vh * 4) = pack4(a4[0], a4[1], a4[2], a4[3]);
    }
    __syncthreads();
  }

  // ---- LayerNorm stats over 96 channels per pixel ----
  if (tid < 64) {
    float s = 0.f, s2 = 0.f;
    for (int c = 0; c < 96; ++c) {
      float ov = bf2f(osh[c * 64 + tid]);
      s += ov; s2 += ov * ov;
    }
    float m = s * (1.f / 96.f);
    float var = s2 * (1.f / 96.f) - m * m;
    mu[tid] = m;
    rs[tid] = rsqrtf(var + 1e-5f);
  }
  __syncthreads();

  // ---- a_t[p][c2] = bf16( v * (normed*gamma + beta) ), aliased over xs_t ----
  for (int u = tid; u < 3072; u += 256) {
    int cp = u >> 6, pp = u & 63, c2 = cp * 2;
    float m = mu[pp], r = rs[pp];
    float o0 = bf2f(osh[c2 * 64 + pp]);
    float o1 = bf2f(osh[(c2 + 1) * 64 + pp]);
    float a0 = ((o0 - m) * r * gam[c2]     + bet[c2])     * bf2f(vsh[c2 * 64 + pp]);
    float a1 = ((o1 - m) * r * gam[c2 + 1] + bet[c2 + 1]) * bf2f(vsh[(c2 + 1) * 64 + pp]);
    *(unsigned int*)(a_t + pp * AT_STR + c2) =
        (unsigned int)f2bf(a0) | ((unsigned int)f2bf(a1) << 16);
  }
  __syncthreads();

  // ---- final conv1x1 (96->48) via MFMA: M=48 x N=64 x K=96, wave = n-tile ----
  {
    int p0 = wv * 16;
    U128 bfr[3];
    #pragma unroll
    for (int ksi = 0; ksi < 3; ++ksi) {
      const unsigned short* bp = a_t + (p0 + ln) * AT_STR + ksi * 32 + quad * 8;
      bfr[ksi].u[0] = *(const unsigned long long*)(bp);
      bfr[ksi].u[1] = *(const unsigned long long*)(bp + 4);
    }
    #pragma unroll
    for (int mt = 0; mt < 3; ++mt) {
      floatx4 acc;
      #pragma unroll
      for (int r = 0; r < 4; ++r) acc[r] = bo[mt * 16 + quad * 4 + r];
      #pragma unroll
      for (int ksi = 0; ksi < 3; ++ksi) {
        short8 af = *(const short8*)(w2 + (mt * 16 + ln) * 96 + ksi * 32 + quad * 8);
        acc = __builtin_amdgcn_mfma_f32_16x16x32_bf16(af, bfr[ksi].s, acc, 0, 0, 0);
      }
      #pragma unroll
      for (int r = 0; r < 4; ++r) {
        int co = mt * 16 + quad * 4 + r;
        y[(((b * C_) + co) * H_ + h) * W_ + w0 + p0 + ln] = acc[r];
      }
    }
  }
}

extern "C" void kernel_launch(void* const* d_in, const int* in_sizes, int n_in,
                              void* d_out, int out_size, void* d_ws, size_t ws_size,
                              hipStream_t stream) {
  const float* x   = (const float*)d_in[0];
  const float* wh  = (const float*)d_in[1];
  const float* bh  = (const float*)d_in[2];
  const float* wdw = (const float*)d_in[3];
  const float* bdw = (const float*)d_in[4];
  const float* g   = (const float*)d_in[5];
  const float* be  = (const float*)d_in[6];
  const float* wo  = (const float*)d_in[7];
  const float* bo  = (const float*)d_in[8];
  float* y = (float*)d_out;
  unsigned short* w1 = (unsigned short*)d_ws;   // 24576 + 4608 ushorts

  fsas_prep<<<dim3(114), 256, 0, stream>>>(wh, wo, w1);
  dim3 grid(4, H_, B_);   // (wseg, h, b) = 4096 blocks
  fsas_fused<<<grid, 256, 0, stream>>>(x, bh, wdw, bdw, g, be, bo, w1, y);
}

// Round 3
// 521.959 us; speedup vs baseline: 2.1540x; 1.4533x over previous
//
#include <hip/hip_runtime.h>

// Fused FSAS: conv1x1(48->288, MFMA) -> depthwise3x3 -> per-64px-segment 8x8
// circular conv (fp32 VALU) -> LayerNorm(96ch) -> v*normed -> conv1x1(96->48,
// K-split MFMA accumulate). v-branch deferred past LN to reuse hid's LDS.
// Block = (wseg, h, b); 3 blocks/CU (LDS 51136 B).

#define B_ 4
#define C_ 48
#define H_ 256
#define W_ 256
#define ROWS 68       // halo row width (66 valid)
#define NPX 208       // 13 n-tiles of 16
#define XT_STR 52     // xs_t ushort stride
#define HID_STR 212   // hid ushort stride
#define QK_STR 68     // qs/ks fp32 stride
#define AV_STR 40     // av ushort stride (16B-aligned rows)

// ---- LDS offsets (bytes) ----
#define OFF_XT  0                    // ushort xs_t[208][52] = 21632
#define OFF_HID 21632                // ushort hid[24][212]  = 10176 (alias: LN partials)
#define OFF_QS  31808                // float qs[12][68] = 3264 (alias: av ushort[64][40]=5120 over qs+ks)
#define OFF_KS  35072                // float ks[12][68] = 3264
#define OFF_OSH 38336                // ushort osh[96][64] = 12288
#define OFF_MU  50624                // float[64]
#define OFF_RS  50880                // float[64]
#define SMEM_BYTES 51136

typedef __attribute__((ext_vector_type(8))) short short8;
typedef __attribute__((ext_vector_type(4))) float floatx4;
union U128 { unsigned long long u[2]; short8 s; };

__device__ __forceinline__ float bf2f(unsigned short u) {
  return __uint_as_float(((unsigned int)u) << 16);
}
__device__ __forceinline__ unsigned short f2bf(float f) {  // RNE
  unsigned int x = __float_as_uint(f);
  x += 0x7FFFu + ((x >> 16) & 1u);
  return (unsigned short)(x >> 16);
}
__device__ __forceinline__ unsigned long long pack4(float a, float b, float c, float d) {
  return (unsigned long long)f2bf(a) | ((unsigned long long)f2bf(b) << 16) |
         ((unsigned long long)f2bf(c) << 32) | ((unsigned long long)f2bf(d) << 48);
}

// ---- weight prep into d_ws (ushort units) ----
// wqk[8][32][64]: rows 0..11=q(c6=ch*12+m), 12..23=k(c6=96+ch*12+m-12), 24..31=0; k>=48 -> 0
// wv1[8][16][64]: rows 0..11=v(c6=192+ch*12+m), 12..15=0; k>=48 -> 0   (at +16384)
// w2p[4][48][32]: [pr][co][kk] = kk<24 ? wo[co*96 + pr*24 + kk] : 0    (at +24576)
__global__ void fsas_prep(const float* __restrict__ wh, const float* __restrict__ wo,
                          unsigned short* __restrict__ ws) {
  int idx = blockIdx.x * 256 + threadIdx.x;
  if (idx < 16384) {
    int kk = idx & 63, t = idx >> 6;
    int m = t & 31, ch = t >> 5;
    float v = 0.f;
    if (kk < 48 && m < 24) {
      int c6 = (m < 12) ? (ch * 12 + m) : (96 + ch * 12 + (m - 12));
      v = wh[c6 * 48 + kk];
    }
    ws[idx] = f2bf(v);
  } else if (idx < 24576) {
    int e = idx - 16384;
    int kk = e & 63, t = e >> 6;
    int m = t & 15, ch = t >> 4;
    float v = 0.f;
    if (kk < 48 && m < 12) v = wh[(192 + ch * 12 + m) * 48 + kk];
    ws[idx] = f2bf(v);
  } else {
    int e = idx - 24576;
    int kk = e & 31, t = e >> 5;
    int co = t % 48, pr = t / 48;
    float v = (kk < 24) ? wo[co * 96 + pr * 24 + kk] : 0.f;
    ws[idx] = f2bf(v);
  }
}

__global__ __launch_bounds__(256, 3) void fsas_fused(
    const float* __restrict__ x,   const float* __restrict__ bh,
    const float* __restrict__ wdw, const float* __restrict__ bdw,
    const float* __restrict__ gam, const float* __restrict__ bet,
    const float* __restrict__ bo,  const unsigned short* __restrict__ ws,
    float* __restrict__ y)
{
  __shared__ __align__(16) char smem[SMEM_BYTES];
  unsigned short* xs_t = (unsigned short*)(smem + OFF_XT);
  unsigned short* hid  = (unsigned short*)(smem + OFF_HID);
  float* qs = (float*)(smem + OFF_QS);
  float* ks = (float*)(smem + OFF_KS);
  unsigned short* osh = (unsigned short*)(smem + OFF_OSH);
  float* mu = (float*)(smem + OFF_MU);
  float* rs = (float*)(smem + OFF_RS);
  unsigned short* avp = (unsigned short*)(smem + OFF_QS);  // alias (v loop)
  float2* part = (float2*)(smem + OFF_HID);                // alias (LN)

  const unsigned short* wqk = ws;
  const unsigned short* wv1 = ws + 16384;
  const unsigned short* w2p = ws + 24576;

  const int tid  = threadIdx.x;
  const int wseg = blockIdx.x;
  const int h    = blockIdx.y;
  const int b    = blockIdx.z;
  const int w0   = wseg * 64;
  const int lane = tid & 63;
  const int wv   = tid >> 6;
  const int ln   = lane & 15;
  const int quad = lane >> 4;

  // ---- Stage A: x halo -> xs_t[p][c] bf16 (all XT_STR cols written: pad=0) ----
  for (int idx = tid; idx < NPX * XT_STR; idx += 256) {
    int p = idx / XT_STR;
    int c = idx - p * XT_STR;
    int rr = p / ROWS, cc = p - rr * ROWS;
    float val = 0.f;
    if (c < C_ && rr < 3 && cc < 66) {
      int gr = h - 1 + rr, gc = w0 - 1 + cc;
      if (gr >= 0 && gr < H_ && gc >= 0 && gc < W_)
        val = x[(((b * C_) + c) * H_ + gr) * W_ + gc];
    }
    xs_t[idx] = f2bf(val);
  }
  __syncthreads();

  // ======== chunk loop: q,k for 12 c2-channels at a time ========
  for (int chunk = 0; chunk < 8; ++chunk) {
    // ---- B1qk: M=24(pad 32) x N=208 x K=48(pad 64) MFMA ----
    short8 aq[2][2];
    #pragma unroll
    for (int mt = 0; mt < 2; ++mt)
      #pragma unroll
      for (int kx = 0; kx < 2; ++kx)
        aq[mt][kx] = *(const short8*)(wqk + ((chunk * 32 + mt * 16 + ln) * 64 + kx * 32 + quad * 8));
    float bqk[2][4];
    #pragma unroll
    for (int mt = 0; mt < 2; ++mt)
      #pragma unroll
      for (int r = 0; r < 4; ++r) {
        int row = mt * 16 + quad * 4 + r;
        float bv = 0.f;
        if (row < 12) bv = bh[chunk * 12 + row];
        else if (row < 24) bv = bh[96 + chunk * 12 + row - 12];
        bqk[mt][r] = bv;
      }
    for (int nt = wv; nt < 13; nt += 4) {
      int p = nt * 16 + ln;
      int rr = p / ROWS, cc = p - rr * ROWS;
      int gr = h - 1 + rr, gc = w0 - 1 + cc;
      bool pv = (rr < 3) && (cc < 66) && (gr >= 0) && (gr < H_) && (gc >= 0) && (gc < W_);
      const unsigned short* bp = xs_t + p * XT_STR + quad * 8;
      U128 b0, b1;
      b0.u[0] = *(const unsigned long long*)(bp);
      b0.u[1] = *(const unsigned long long*)(bp + 4);
      b1.u[0] = *(const unsigned long long*)(bp + 32);   // k>=48 junk * zero-A = 0
      b1.u[1] = *(const unsigned long long*)(bp + 36);
      #pragma unroll
      for (int mt = 0; mt < 2; ++mt) {
        floatx4 acc = {bqk[mt][0], bqk[mt][1], bqk[mt][2], bqk[mt][3]};
        acc = __builtin_amdgcn_mfma_f32_16x16x32_bf16(aq[mt][0], b0.s, acc, 0, 0, 0);
        acc = __builtin_amdgcn_mfma_f32_16x16x32_bf16(aq[mt][1], b1.s, acc, 0, 0, 0);
        if (mt == 0) {
          #pragma unroll
          for (int r = 0; r < 4; ++r)
            hid[(quad * 4 + r) * HID_STR + p] = pv ? f2bf(acc[r]) : (unsigned short)0;
        } else if (quad < 2) {
          #pragma unroll
          for (int r = 0; r < 4; ++r)
            hid[(16 + quad * 4 + r) * HID_STR + p] = pv ? f2bf(acc[r]) : (unsigned short)0;
        }
      }
    }
    __syncthreads();

    // ---- B2qk: depthwise 3x3 -> qs/ks fp32 (192 units of 8px) ----
    if (tid < 192) {
      int cl = tid >> 3, pg = tid & 7, p0 = pg * 8;
      int lc = (cl < 12) ? cl : cl - 12;
      int c6 = (cl < 12) ? (chunk * 12 + cl) : (96 + chunk * 12 + lc);
      const float* wd = wdw + c6 * 9;
      float bb = bdw[c6];
      float a8[8];
      #pragma unroll
      for (int t = 0; t < 8; ++t) a8[t] = bb;
      #pragma unroll
      for (int di = 0; di < 3; ++di) {
        const unsigned short* hrow = hid + cl * HID_STR + di * ROWS + p0;
        unsigned long long lo = *(const unsigned long long*)(hrow);
        unsigned long long hi = *(const unsigned long long*)(hrow + 4);
        unsigned int ex = *(const unsigned int*)(hrow + 8);
        float hf[10];
        #pragma unroll
        for (int t = 0; t < 4; ++t) hf[t] = bf2f((unsigned short)(lo >> (16 * t)));
        #pragma unroll
        for (int t = 0; t < 4; ++t) hf[4 + t] = bf2f((unsigned short)(hi >> (16 * t)));
        hf[8] = bf2f((unsigned short)ex);
        hf[9] = bf2f((unsigned short)(ex >> 16));
        #pragma unroll
        for (int dj = 0; dj < 3; ++dj) {
          float w = wd[di * 3 + dj];
          #pragma unroll
          for (int t = 0; t < 8; ++t) a8[t] += w * hf[t + dj];
        }
      }
      float* dst = ((cl < 12) ? qs : ks) + lc * QK_STR + p0;
      *(float4*)(dst)     = make_float4(a8[0], a8[1], a8[2], a8[3]);
      *(float4*)(dst + 4) = make_float4(a8[4], a8[5], a8[6], a8[7]);
    }
    __syncthreads();

    // ---- B3: 8x8 circular conv, fp32, 192 threads (cl, u, vhalf) ----
    if (tid < 192) {
      int cl = tid >> 4, r4 = tid & 15, uu = r4 >> 1, vh = r4 & 1;
      const float* qrow = qs + cl * QK_STR;
      const float* krow = ks + cl * QK_STR;
      float a4[4] = {0.f, 0.f, 0.f, 0.f};
      #pragma unroll
      for (int i = 0; i < 8; ++i) {
        float4 q0 = *(const float4*)(qrow + i * 8);
        float4 q1 = *(const float4*)(qrow + i * 8 + 4);
        int ri = (uu - i) & 7;
        float4 ka = *(const float4*)(krow + ri * 8 + vh * 4);       // rotated-by-4 if vh
        float4 kb = *(const float4*)(krow + ri * 8 + (vh ^ 1) * 4);
        float qf[8] = {q0.x, q0.y, q0.z, q0.w, q1.x, q1.y, q1.z, q1.w};
        float kr[8] = {ka.x, ka.y, ka.z, ka.w, kb.x, kb.y, kb.z, kb.w};
        #pragma unroll
        for (int vvi = 0; vvi < 4; ++vvi)
          #pragma unroll
          for (int j = 0; j < 8; ++j)
            a4[vvi] += qf[j] * kr[(vvi - j) & 7];
      }
      int c2 = chunk * 12 + cl;
      *(unsigned long long*)(osh + c2 * 64 + uu * 8 + vh * 4) = pack4(a4[0], a4[1], a4[2], a4[3]);
    }
    __syncthreads();
  }

  // ======== LayerNorm stats (parallel: 4 channel-segments x 64 px) ========
  {
    int p = tid & 63, seg = tid >> 6;
    float s = 0.f, s2 = 0.f;
    for (int c = seg * 24; c < seg * 24 + 24; ++c) {
      float ov = bf2f(osh[c * 64 + p]);
      s += ov; s2 += ov * ov;
    }
    part[seg * 64 + p] = make_float2(s, s2);
  }
  __syncthreads();
  if (tid < 64) {
    float s = 0.f, s2 = 0.f;
    #pragma unroll
    for (int seg = 0; seg < 4; ++seg) {
      float2 pr2 = part[seg * 64 + tid];
      s += pr2.x; s2 += pr2.y;
    }
    float m = s * (1.f / 96.f);
    float var = s2 * (1.f / 96.f) - m * m;
    mu[tid] = m;
    rs[tid] = rsqrtf(var + 1e-5f);
  } else if (tid < 128) {
    int p = tid - 64;   // zero av k-pad rows 24..31 (persist: never overwritten)
    *(unsigned long long*)(avp + p * AV_STR + 24) = 0ull;
    *(unsigned long long*)(avp + p * AV_STR + 28) = 0ull;
  }
  __syncthreads();

  // ======== v loop: deferred v-branch + K-split final conv accumulate ========
  floatx4 oacc[3];
  #pragma unroll
  for (int mt = 0; mt < 3; ++mt)
    #pragma unroll
    for (int r = 0; r < 4; ++r) oacc[mt][r] = bo[mt * 16 + quad * 4 + r];

  for (int pr = 0; pr < 4; ++pr) {
    #pragma unroll
    for (int half = 0; half < 2; ++half) {
      int chunk = pr * 2 + half;
      // B1v: M=12(pad 16) x 208 x 48
      short8 av0 = *(const short8*)(wv1 + ((chunk * 16 + ln) * 64 + quad * 8));
      short8 av1 = *(const short8*)(wv1 + ((chunk * 16 + ln) * 64 + 32 + quad * 8));
      float bvv[4];
      #pragma unroll
      for (int r = 0; r < 4; ++r) {
        int row = quad * 4 + r;
        bvv[r] = (row < 12) ? bh[192 + chunk * 12 + row] : 0.f;
      }
      for (int nt = wv; nt < 13; nt += 4) {
        int p = nt * 16 + ln;
        int rr = p / ROWS, cc = p - rr * ROWS;
        int gr = h - 1 + rr, gc = w0 - 1 + cc;
        bool pv = (rr < 3) && (cc < 66) && (gr >= 0) && (gr < H_) && (gc >= 0) && (gc < W_);
        const unsigned short* bp = xs_t + p * XT_STR + quad * 8;
        U128 b0, b1;
        b0.u[0] = *(const unsigned long long*)(bp);
        b0.u[1] = *(const unsigned long long*)(bp + 4);
        b1.u[0] = *(const unsigned long long*)(bp + 32);
        b1.u[1] = *(const unsigned long long*)(bp + 36);
        floatx4 acc = {bvv[0], bvv[1], bvv[2], bvv[3]};
        acc = __builtin_amdgcn_mfma_f32_16x16x32_bf16(av0, b0.s, acc, 0, 0, 0);
        acc = __builtin_amdgcn_mfma_f32_16x16x32_bf16(av1, b1.s, acc, 0, 0, 0);
        if (quad < 3) {
          #pragma unroll
          for (int r = 0; r < 4; ++r)
            hid[(quad * 4 + r) * HID_STR + p] = pv ? f2bf(acc[r]) : (unsigned short)0;
        }
      }
      __syncthreads();
      // B2v + epilogue: av[p][half*12+lc] = bf16(normed * v)
      if (tid < 96) {
        int lc = tid % 12, pg = tid / 12, p0 = pg * 8;
        int c2 = chunk * 12 + lc, c6 = 192 + c2;
        const float* wd = wdw + c6 * 9;
        float bb = bdw[c6];
        float a8[8];
        #pragma unroll
        for (int t = 0; t < 8; ++t) a8[t] = bb;
        #pragma unroll
        for (int di = 0; di < 3; ++di) {
          const unsigned short* hrow = hid + lc * HID_STR + di * ROWS + p0;
          unsigned long long lo = *(const unsigned long long*)(hrow);
          unsigned long long hi = *(const unsigned long long*)(hrow + 4);
          unsigned int ex = *(const unsigned int*)(hrow + 8);
          float hf[10];
          #pragma unroll
          for (int t = 0; t < 4; ++t) hf[t] = bf2f((unsigned short)(lo >> (16 * t)));
          #pragma unroll
          for (int t = 0; t < 4; ++t) hf[4 + t] = bf2f((unsigned short)(hi >> (16 * t)));
          hf[8] = bf2f((unsigned short)ex);
          hf[9] = bf2f((unsigned short)(ex >> 16));
          #pragma unroll
          for (int dj = 0; dj < 3; ++dj) {
            float w = wd[di * 3 + dj];
            #pragma unroll
            for (int t = 0; t < 8; ++t) a8[t] += w * hf[t + dj];
          }
        }
        float gv = gam[c2], bev = bet[c2];
        #pragma unroll
        for (int t = 0; t < 8; ++t) {
          int p = p0 + t;
          float o = bf2f(osh[c2 * 64 + p]);
          float a = ((o - mu[p]) * rs[p] * gv + bev) * a8[t];
          avp[p * AV_STR + half * 12 + lc] = f2bf(a);
        }
      }
      __syncthreads();
    }
    // final-conv K-split MFMA: K rows 0..23 = c2 24*pr..+23, rows 24..31 = 0
    {
      const unsigned short* bp = avp + (wv * 16 + ln) * AV_STR + quad * 8;
      U128 bfr;
      bfr.u[0] = *(const unsigned long long*)(bp);
      bfr.u[1] = *(const unsigned long long*)(bp + 4);
      #pragma unroll
      for (int mt = 0; mt < 3; ++mt) {
        short8 af = *(const short8*)(w2p + ((pr * 48 + mt * 16 + ln) * 32 + quad * 8));
        oacc[mt] = __builtin_amdgcn_mfma_f32_16x16x32_bf16(af, bfr.s, oacc[mt], 0, 0, 0);
      }
    }
  }

  // ---- store y ----
  #pragma unroll
  for (int mt = 0; mt < 3; ++mt)
    #pragma unroll
    for (int r = 0; r < 4; ++r) {
      int co = mt * 16 + quad * 4 + r;
      y[(((b * C_) + co) * H_ + h) * W_ + w0 + wv * 16 + ln] = oacc[mt][r];
    }
}

extern "C" void kernel_launch(void* const* d_in, const int* in_sizes, int n_in,
                              void* d_out, int out_size, void* d_ws, size_t ws_size,
                              hipStream_t stream) {
  const float* x   = (const float*)d_in[0];
  const float* wh  = (const float*)d_in[1];
  const float* bh  = (const float*)d_in[2];
  const float* wdw = (const float*)d_in[3];
  const float* bdw = (const float*)d_in[4];
  const float* g   = (const float*)d_in[5];
  const float* be  = (const float*)d_in[6];
  const float* wo  = (const float*)d_in[7];
  const float* bo  = (const float*)d_in[8];
  float* y = (float*)d_out;
  unsigned short* ws = (unsigned short*)d_ws;   // 30720 ushorts

  fsas_prep<<<dim3(120), 256, 0, stream>>>(wh, wo, ws);
  dim3 grid(4, H_, B_);
  fsas_fused<<<grid, 256, 0, stream>>>(x, bh, wdw, bdw, g, be, bo, ws, y);
}